// Round 7
// baseline (5687.211 us; speedup 1.0000x reference)
//
#include <hip/hip_runtime.h>
#include <hip/hip_bf16.h>
#include <stdint.h>

typedef __attribute__((ext_vector_type(8))) short short8;
typedef __attribute__((ext_vector_type(4))) float floatx4;

#define B_ 64
#define T_ 256
#define H_ 1024
#define LATENT_ 256
#define P_ 128
#define BH_ (B_ * H_)
#define MFMA_(a, b, c) __builtin_amdgcn_mfma_f32_16x16x32_bf16(a, b, c, 0, 0, 0)
// LDS column swizzle: breaks the 16-way bank conflict on cell-phase reads
// (write side stays <=2-way). pbuf is exactly 64 KB so no room for +1 pad.
#define PBI(n, row) (((n) + 4 * (row)) & 31)

__device__ __forceinline__ float sigmoidf_(float x) {
    return 1.0f / (1.0f + __expf(-x));
}
__device__ __forceinline__ float tanh_fast(float x) {
    float e = __expf(2.0f * x);
    return 1.0f - 2.0f / (e + 1.0f);
}

// Agent-scope (device) 16B A-fragment load as 2x8B atomic loads: emits
// global_load_dwordx2 with sc1 -> bypasses the reader's (possibly stale,
// non-coherent) XCD L2 and reads from L3 where sc1 stores landed.
// NOTE (R6 lesson): these are kept in PROGRAM ORDER by the backend and each
// gets a waitcnt before its consumer -> issue ALL of them before ANY MFMA.
__device__ __forceinline__ short8 ldA_sc(const short* p) {
    union { unsigned long long u[2]; short8 s; } v;
    const unsigned long long* q = (const unsigned long long*)p;
    v.u[0] = __hip_atomic_load(q,     __ATOMIC_RELAXED, __HIP_MEMORY_SCOPE_AGENT);
    v.u[1] = __hip_atomic_load(q + 1, __ATOMIC_RELAXED, __HIP_MEMORY_SCOPE_AGENT);
    return v.s;
}

// ---------------------------------------------------------------------------
__global__ __launch_bounds__(256) void cvt_f2b(
    const float* __restrict__ src, __hip_bfloat16* __restrict__ dst, int n)
{
    int i = (blockIdx.x * 256 + threadIdx.x) * 4;
    if (i < n) {
        float4 v = *(const float4*)(src + i);
        dst[i + 0] = __float2bfloat16(v.x);
        dst[i + 1] = __float2bfloat16(v.y);
        dst[i + 2] = __float2bfloat16(v.z);
        dst[i + 3] = __float2bfloat16(v.w);
    }
}

// h0 = z @ fc_init_w^T + fc_init_b -> both t=-1 ring slots; zero barrier
// counters (8 lines) + release flag (9th line).
__global__ __launch_bounds__(256) void h0_kernel(
    const float* __restrict__ z,
    const float* __restrict__ fw,
    const float* __restrict__ fb,
    __hip_bfloat16* __restrict__ h1dst,
    __hip_bfloat16* __restrict__ h2dst,
    unsigned* __restrict__ cnt)
{
    if (blockIdx.x == 0 && threadIdx.x < 9) cnt[threadIdx.x * 64] = 0;
    int idx = blockIdx.x * 256 + threadIdx.x;   // 0..65535
    int b = idx >> 10, j = idx & 1023;
    const float* zp = z + b * LATENT_;
    const float* wp = fw + j * LATENT_;
    float acc = fb[j];
    for (int k = 0; k < LATENT_; k += 4) {
        float4 zv = *(const float4*)(zp + k);
        float4 wv = *(const float4*)(wp + k);
        acc += zv.x * wv.x + zv.y * wv.y + zv.z * wv.z + zv.w * wv.w;
    }
    __hip_bfloat16 hb = __float2bfloat16(acc);
    h1dst[idx] = hb;
    h2dst[idx] = hb;
}

struct PParams {
    const __hip_bfloat16 *tseqb, *stokb;
    const __hip_bfloat16 *Wih0b, *Whh0b, *Wih1b, *Whh1b, *owb;
    const float *bih0, *bhh0, *bih1, *bhh1, *ob;
    __hip_bfloat16 *h1ring;   // 2 * B*H
    __hip_bfloat16 *h2ring;   // 4 * B*H
    float* out;               // (B, T, P)
    unsigned* cnt;            // 8 arrive counters (256B apart) + flag line
};

// ---------------------------------------------------------------------------
// Persistent pipelined LSTM. 256 blocks x 512 threads (8 waves), 1 block/CU.
//   blocks   0..127 : layer-1 step t=phase-1, 8 cols x 4 gates (N=32 rows)
//   blocks 128..255 : layer-0 step t=phase
//   blocks 128..135 : + out-projection of step phase-2
// R6 post-mortem: the phase cost was 32 SERIALIZED (L3-load -> MFMA) units
// (atomic loads keep program order; waitcnt before each use). Fix: preload
// the entire K-segment's A-fragments into registers (all loads in flight
// together), then run all MFMAs.
// ---------------------------------------------------------------------------
__global__ __launch_bounds__(512, 2) void lstm_persistent(PParams p)
{
    __shared__ float pbuf[8][64][32];   // 64 KB partial-sum exchange
    const int tid  = threadIdx.x;
    const int bid  = blockIdx.x;
    const int wv   = tid >> 6;
    const int l    = tid & 63;
    const int l15  = l & 15;
    const int quad = l >> 4;
    const int ks   = quad * 8;
    const bool isL1 = bid < 128;
    const int colbase = (isL1 ? bid : bid - 128) * 8;
    // B-frag weight rows: nt=0 -> gates {i,f}, nt=1 -> gates {g,o}
    const int row0 = ((l15 >> 3)    ) * H_ + colbase + (l15 & 7);
    const int row1 = ((l15 >> 3) + 2) * H_ + colbase + (l15 & 7);

    // Cell duty: threads 0..255, two adjacent cells each (uint h-store).
    const int cm  = tid >> 2;          // batch row
    const int c0  = 2 * (tid & 3);     // first of the col pair
    const int cj0 = colbase + c0;
    const float* bi = isL1 ? p.bih1 : p.bih0;
    const float* bh = isL1 ? p.bhh1 : p.bhh0;
    float bs[8];                       // {i,f,g,o} x {c0, c0+1}
#pragma unroll
    for (int g = 0; g < 4; ++g) {
        bs[2 * g]     = bi[g * H_ + cj0]     + bh[g * H_ + cj0];
        bs[2 * g + 1] = bi[g * H_ + cj0 + 1] + bh[g * H_ + cj0 + 1];
    }
    float creg0 = 0.0f, creg1 = 0.0f;
    const bool outduty = (bid >= 128 && bid < 136);
    const int pbase = (bid - 128) * 16;
    unsigned* const flag = p.cnt + 8 * 64;   // release generation line

    for (int phase = 0; phase < T_ + 2; ++phase) {
        const bool doGemm = isL1 ? (phase >= 1 && phase <= T_) : (phase < T_);
        const int t = isL1 ? phase - 1 : phase;

        if (doGemm) {
            floatx4 acc[8] = {};
            if (isL1) {
                // gates1 = [h1(t) | h2(t-1)] @ [Wih1 | Whh1]^T, K=2048.
                // Wave K-segment: 8 chunks of 32. Preload ALL 32 A-frags.
                const short* Ab; const short* Wm; int kb;
                if (wv < 4) {
                    Ab = (const short*)p.h1ring + (long)(t & 1) * BH_;
                    Wm = (const short*)p.Wih1b;  kb = wv * 256;
                } else {
                    Ab = (const short*)p.h2ring + (long)((t - 1) & 3) * BH_;
                    Wm = (const short*)p.Whh1b;  kb = (wv - 4) * 256;
                }
                const short* A  = Ab + kb + ks;
                const short* w0 = Wm + (long)row0 * H_ + kb + ks;
                const short* w1 = Wm + (long)row1 * H_ + kb + ks;
                short8 af[32];
#pragma unroll
                for (int c = 0; c < 8; ++c)
#pragma unroll
                    for (int mt = 0; mt < 4; ++mt)
                        af[c * 4 + mt] = ldA_sc(A + (long)(mt * 16 + l15) * H_ + c * 32);
#pragma unroll
                for (int c = 0; c < 8; ++c) {
                    short8 b0 = *(const short8*)(w0 + c * 32);
                    short8 b1 = *(const short8*)(w1 + c * 32);
#pragma unroll
                    for (int mt = 0; mt < 4; ++mt) {
                        acc[2 * mt]     = MFMA_(af[c * 4 + mt], b0, acc[2 * mt]);
                        acc[2 * mt + 1] = MFMA_(af[c * 4 + mt], b1, acc[2 * mt + 1]);
                    }
                }
            } else {
                // gates0 = [x_t | h1(t-1)] @ [Wih0 | Whh0]^T, K=128+1024.
                // Preload 16 h-frags (sc1) + 4 x-frags (normal) up front.
                const short* Ah  = (const short*)p.h1ring
                                 + (long)((t - 1) & 1) * BH_ + wv * 128 + ks;
                const short* w0h = (const short*)p.Whh0b + (long)row0 * H_ + wv * 128 + ks;
                const short* w1h = (const short*)p.Whh0b + (long)row1 * H_ + wv * 128 + ks;
                const short* Ax; long xstr;
                if (t == 0) { Ax = (const short*)p.stokb; xstr = 0; }
                else { Ax = (const short*)p.tseqb + (long)(t - 1) * P_; xstr = (long)T_ * P_; }
                short8 af[16];
#pragma unroll
                for (int c = 0; c < 4; ++c)
#pragma unroll
                    for (int mt = 0; mt < 4; ++mt)
                        af[c * 4 + mt] = ldA_sc(Ah + (long)(mt * 16 + l15) * H_ + c * 32);
                short8 xf[4];
                if (wv < 4) {
#pragma unroll
                    for (int mt = 0; mt < 4; ++mt)
                        xf[mt] = *(const short8*)(Ax + (long)(mt * 16 + l15) * xstr + wv * 32 + ks);
                }
#pragma unroll
                for (int c = 0; c < 4; ++c) {
                    short8 b0 = *(const short8*)(w0h + c * 32);
                    short8 b1 = *(const short8*)(w1h + c * 32);
#pragma unroll
                    for (int mt = 0; mt < 4; ++mt) {
                        acc[2 * mt]     = MFMA_(af[c * 4 + mt], b0, acc[2 * mt]);
                        acc[2 * mt + 1] = MFMA_(af[c * 4 + mt], b1, acc[2 * mt + 1]);
                    }
                }
                if (wv < 4) {   // x-part chunk wv
                    short8 b0 = *(const short8*)((const short*)p.Wih0b + (long)row0 * P_ + wv * 32 + ks);
                    short8 b1 = *(const short8*)((const short*)p.Wih0b + (long)row1 * P_ + wv * 32 + ks);
#pragma unroll
                    for (int mt = 0; mt < 4; ++mt) {
                        acc[2 * mt]     = MFMA_(xf[mt], b0, acc[2 * mt]);
                        acc[2 * mt + 1] = MFMA_(xf[mt], b1, acc[2 * mt + 1]);
                    }
                }
            }
            // C/D: col = lane&15, row = quad*4 + reg (+ mt*16)
#pragma unroll
            for (int mt = 0; mt < 4; ++mt)
#pragma unroll
                for (int nt = 0; nt < 2; ++nt)
#pragma unroll
                    for (int r = 0; r < 4; ++r) {
                        int row = mt * 16 + quad * 4 + r;
                        pbuf[wv][row][PBI(nt * 16 + l15, row)] = acc[2 * mt + nt][r];
                    }
        }
        __syncthreads();
        if (doGemm && tid < 256) {
            // gate n-layout: i: [0,8) f: [8,16) g: [16,24) o: [24,32)
            float v[8];
#pragma unroll
            for (int k = 0; k < 8; ++k) v[k] = bs[k];
#pragma unroll
            for (int w2 = 0; w2 < 8; ++w2)
#pragma unroll
                for (int g = 0; g < 4; ++g) {
                    v[2 * g]     += pbuf[w2][cm][PBI(8 * g + c0,     cm)];
                    v[2 * g + 1] += pbuf[w2][cm][PBI(8 * g + c0 + 1, cm)];
                }
            float cn0 = sigmoidf_(v[2]) * creg0 + sigmoidf_(v[0]) * tanh_fast(v[4]);
            float cn1 = sigmoidf_(v[3]) * creg1 + sigmoidf_(v[1]) * tanh_fast(v[5]);
            float hv0 = sigmoidf_(v[6]) * tanh_fast(cn0);
            float hv1 = sigmoidf_(v[7]) * tanh_fast(cn1);
            creg0 = cn0; creg1 = cn1;
            __hip_bfloat16* hdst = isL1 ? (p.h2ring + (long)(t & 3) * BH_)
                                        : (p.h1ring + (long)(t & 1) * BH_);
            __hip_bfloat16 hb0 = __float2bfloat16(hv0), hb1 = __float2bfloat16(hv1);
            unsigned pk = ((unsigned)*(unsigned short*)&hb1 << 16) | *(unsigned short*)&hb0;
            // sc1 write-through -> visible at L3 once vmcnt-drained.
            __hip_atomic_store((unsigned*)(hdst + cm * H_ + cj0), pk,
                               __ATOMIC_RELAXED, __HIP_MEMORY_SCOPE_AGENT);
        }

        if (outduty && phase >= 2) {
            int t2 = phase - 2;
            __syncthreads();   // cell reads of pbuf done; safe to overwrite
            floatx4 oacc[4] = {};
            const short* Ab = (const short*)p.h2ring + (long)(t2 & 3) * BH_ + wv * 128 + ks;
            const short* Wb = (const short*)p.owb + (long)(pbase + l15) * H_ + wv * 128 + ks;
            short8 of[16];
#pragma unroll
            for (int c2 = 0; c2 < 4; ++c2)
#pragma unroll
                for (int mt = 0; mt < 4; ++mt)
                    of[c2 * 4 + mt] = ldA_sc(Ab + (long)(mt * 16 + l15) * H_ + c2 * 32);
#pragma unroll
            for (int c2 = 0; c2 < 4; ++c2) {
                short8 b0 = *(const short8*)(Wb + c2 * 32);
#pragma unroll
                for (int mt = 0; mt < 4; ++mt)
                    oacc[mt] = MFMA_(of[c2 * 4 + mt], b0, oacc[mt]);
            }
#pragma unroll
            for (int mt = 0; mt < 4; ++mt)
#pragma unroll
                for (int r = 0; r < 4; ++r)
                    pbuf[wv][mt * 16 + quad * 4 + r][l15] = oacc[mt][r];
            __syncthreads();
#pragma unroll
            for (int q2 = 0; q2 < 2; ++q2) {
                int e = tid + q2 * 512, m = e >> 4, pp = e & 15;
                float v = p.ob[pbase + pp];
#pragma unroll
                for (int w2 = 0; w2 < 8; ++w2) v += pbuf[w2][m][pp];
                p.out[(long)m * (T_ * P_) + (long)t2 * P_ + pbase + pp] = sigmoidf_(v);
            }
        }

        // __syncthreads drains each wave's vmcnt(0) (h stores complete at L3)
        __syncthreads();
        if (tid == 0) {
            __hip_atomic_fetch_add(p.cnt + (bid & 7) * 64, 1u,
                                   __ATOMIC_RELAXED, __HIP_MEMORY_SCOPE_AGENT);
            unsigned gen = (unsigned)(phase + 1);
            if (bid == 0) {
                // Leader: aggregate the 8 arrive counters, then publish gen.
                unsigned target = 256u * gen;
                for (;;) {
                    unsigned s = 0;
#pragma unroll
                    for (int i2 = 0; i2 < 8; ++i2)
                        s += __hip_atomic_load(p.cnt + i2 * 64,
                                               __ATOMIC_RELAXED, __HIP_MEMORY_SCOPE_AGENT);
                    if (s >= target) break;
                    __builtin_amdgcn_s_sleep(1);
                }
                asm volatile("" ::: "memory");
                __hip_atomic_store(flag, gen,
                                   __ATOMIC_RELAXED, __HIP_MEMORY_SCOPE_AGENT);
            } else {
                // Everyone else polls ONE line with backoff (no read storm).
                while (__hip_atomic_load(flag, __ATOMIC_RELAXED,
                                         __HIP_MEMORY_SCOPE_AGENT) < gen)
                    __builtin_amdgcn_s_sleep(8);
            }
        }
        asm volatile("" ::: "memory");   // compiler fence: no hoisting past spin
        __syncthreads();
    }
}

// ---------------------------------------------------------------------------
extern "C" void kernel_launch(void* const* d_in, const int* in_sizes, int n_in,
                              void* d_out, int out_size, void* d_ws, size_t ws_size,
                              hipStream_t stream) {
    const float* z    = (const float*)d_in[0];
    const float* tseq = (const float*)d_in[1];
    const float* fw   = (const float*)d_in[2];
    const float* fb   = (const float*)d_in[3];
    const float* stok = (const float*)d_in[4];
    const float* Wih0 = (const float*)d_in[5];
    const float* Whh0 = (const float*)d_in[6];
    const float* bih0 = (const float*)d_in[7];
    const float* bhh0 = (const float*)d_in[8];
    const float* Wih1 = (const float*)d_in[9];
    const float* Whh1 = (const float*)d_in[10];
    const float* bih1 = (const float*)d_in[11];
    const float* bhh1 = (const float*)d_in[12];
    const float* ow   = (const float*)d_in[13];
    const float* ob   = (const float*)d_in[14];
    float* out = (float*)d_out;

    // Workspace (~30.2 MB)
    char* ws = (char*)d_ws;
    size_t off = 0;
    __hip_bfloat16* Wih0b = (__hip_bfloat16*)(ws + off); off += (size_t)4 * H_ * P_ * 2;
    __hip_bfloat16* Whh0b = (__hip_bfloat16*)(ws + off); off += (size_t)4 * H_ * H_ * 2;
    __hip_bfloat16* Wih1b = (__hip_bfloat16*)(ws + off); off += (size_t)4 * H_ * H_ * 2;
    __hip_bfloat16* Whh1b = (__hip_bfloat16*)(ws + off); off += (size_t)4 * H_ * H_ * 2;
    __hip_bfloat16* owb   = (__hip_bfloat16*)(ws + off); off += (size_t)P_ * H_ * 2;
    __hip_bfloat16* tseqb = (__hip_bfloat16*)(ws + off); off += (size_t)B_ * T_ * P_ * 2;
    __hip_bfloat16* stokb = (__hip_bfloat16*)(ws + off); off += 256;
    __hip_bfloat16* h1ring= (__hip_bfloat16*)(ws + off); off += (size_t)2 * BH_ * 2;
    __hip_bfloat16* h2ring= (__hip_bfloat16*)(ws + off); off += (size_t)4 * BH_ * 2;
    unsigned* cnt         = (unsigned*)(ws + off);       off += 9 * 256;

    auto cvt = [&](const float* s, __hip_bfloat16* d, int n) {
        hipLaunchKernelGGL(cvt_f2b, dim3((n / 4 + 255) / 256), dim3(256), 0, stream, s, d, n);
    };
    cvt(Wih0, Wih0b, 4 * H_ * P_);
    cvt(Whh0, Whh0b, 4 * H_ * H_);
    cvt(Wih1, Wih1b, 4 * H_ * H_);
    cvt(Whh1, Whh1b, 4 * H_ * H_);
    cvt(ow,   owb,   P_ * H_);
    cvt(tseq, tseqb, B_ * T_ * P_);
    cvt(stok, stokb, P_);

    // h0 into t=-1 slots: h1 slot (-1)&1 = 1, h2 slot (-1)&3 = 3.
    hipLaunchKernelGGL(h0_kernel, dim3(256), dim3(256), 0, stream,
                       z, fw, fb, h1ring + (size_t)1 * BH_, h2ring + (size_t)3 * BH_, cnt);

    PParams pp;
    pp.tseqb = tseqb; pp.stokb = stokb;
    pp.Wih0b = Wih0b; pp.Whh0b = Whh0b; pp.Wih1b = Wih1b; pp.Whh1b = Whh1b;
    pp.owb = owb;
    pp.bih0 = bih0; pp.bhh0 = bhh0; pp.bih1 = bih1; pp.bhh1 = bhh1; pp.ob = ob;
    pp.h1ring = h1ring; pp.h2ring = h2ring;
    pp.out = out;
    pp.cnt = cnt;
    void* args[] = { &pp };
    hipLaunchCooperativeKernel((void*)lstm_persistent, dim3(256), dim3(512),
                               args, 0, stream);
}

// Round 8
// 3715.803 us; speedup vs baseline: 1.5305x; 1.5305x over previous
//
#include <hip/hip_runtime.h>
#include <hip/hip_bf16.h>
#include <stdint.h>

typedef __attribute__((ext_vector_type(8))) short short8;
typedef __attribute__((ext_vector_type(4))) float floatx4;

#define B_ 64
#define T_ 256
#define H_ 1024
#define LATENT_ 256
#define P_ 128
#define BH_ (B_ * H_)
#define MFMA_(a, b, c) __builtin_amdgcn_mfma_f32_16x16x32_bf16(a, b, c, 0, 0, 0)
// LDS column swizzle: breaks the 16-way bank conflict on cell-phase reads.
#define PBI(n, row) (((n) + 4 * (row)) & 31)

__device__ __forceinline__ float sigmoidf_(float x) {
    return 1.0f / (1.0f + __expf(-x));
}
__device__ __forceinline__ float tanh_fast(float x) {
    float e = __expf(2.0f * x);
    return 1.0f - 2.0f / (e + 1.0f);
}

// L2-bypassing (agent/sc1) 16B load — only needed in RING mode where h slot
// addresses are reused and a reader's XCD L2 may be stale. Throughput wall
// measured R5-R7: ~2.3 TB/s chip-wide -> 21 us/phase. Avoid when possible.
__device__ __forceinline__ short8 ldA_sc(const short* p) {
    union { unsigned long long u[2]; short8 s; } v;
    const unsigned long long* q = (const unsigned long long*)p;
    v.u[0] = __hip_atomic_load(q,     __ATOMIC_RELAXED, __HIP_MEMORY_SCOPE_AGENT);
    v.u[1] = __hip_atomic_load(q + 1, __ATOMIC_RELAXED, __HIP_MEMORY_SCOPE_AGENT);
    return v.s;
}
template <bool RING>
__device__ __forceinline__ short8 ldA(const short* p) {
    if (RING) return ldA_sc(p);
    return *(const short8*)p;   // write-once addresses -> normal cached load
}

// ---------------------------------------------------------------------------
__global__ __launch_bounds__(256) void cvt_f2b(
    const float* __restrict__ src, __hip_bfloat16* __restrict__ dst, int n)
{
    int i = (blockIdx.x * 256 + threadIdx.x) * 4;
    if (i < n) {
        float4 v = *(const float4*)(src + i);
        dst[i + 0] = __float2bfloat16(v.x);
        dst[i + 1] = __float2bfloat16(v.y);
        dst[i + 2] = __float2bfloat16(v.z);
        dst[i + 3] = __float2bfloat16(v.w);
    }
}

// h0 = z @ fc_init_w^T + fc_init_b -> the two t=-1 slots; zero barrier lines.
__global__ __launch_bounds__(256) void h0_kernel(
    const float* __restrict__ z,
    const float* __restrict__ fw,
    const float* __restrict__ fb,
    __hip_bfloat16* __restrict__ h1dst,
    __hip_bfloat16* __restrict__ h2dst,
    unsigned* __restrict__ cnt)
{
    if (blockIdx.x == 0 && threadIdx.x < 9) cnt[threadIdx.x * 64] = 0;
    int idx = blockIdx.x * 256 + threadIdx.x;   // 0..65535
    int b = idx >> 10, j = idx & 1023;
    const float* zp = z + b * LATENT_;
    const float* wp = fw + j * LATENT_;
    float acc = fb[j];
    for (int k = 0; k < LATENT_; k += 4) {
        float4 zv = *(const float4*)(zp + k);
        float4 wv = *(const float4*)(wp + k);
        acc += zv.x * wv.x + zv.y * wv.y + zv.z * wv.z + zv.w * wv.w;
    }
    __hip_bfloat16 hb = __float2bfloat16(acc);
    h1dst[idx] = hb;
    h2dst[idx] = hb;
}

struct PParams {
    const __hip_bfloat16 *tseqb, *stokb;
    const __hip_bfloat16 *Wih0b, *Whh0b, *Wih1b, *Whh1b, *owb;
    const float *bih0, *bhh0, *bih1, *bhh1, *ob;
    __hip_bfloat16 *h1seq;    // RING ? 2 slots : T+1 slots (write-once per t)
    __hip_bfloat16 *h2seq;    // RING ? 4 slots : T+1 slots
    float* out;               // (B, T, P)
    unsigned* cnt;            // 8 arrive counters (256B apart) + flag line
};

// ---------------------------------------------------------------------------
// Persistent pipelined LSTM. 256 blocks x 512 threads (8 waves), 1 block/CU.
//   blocks   0..127 : layer-1 step t=phase-1 (8 cols x 4 gates, N=32 rows)
//   blocks 128..255 : layer-0 step t=phase
//   blocks 128..135 : + out-projection of step phase-2
// RING=false (preferred): h slots are write-once addresses -> consumers use
// NORMAL L2-cached loads (stale-line-free by construction + dispatch-start
// L2 invalidate). Producers still store via sc1 write-through so the LLC
// always holds the truth. RING=true: R7 behavior (sc1 reads), ws fallback.
// ---------------------------------------------------------------------------
template <bool RING>
__global__ __launch_bounds__(512, 2) void lstm_persistent(PParams p)
{
    __shared__ float pbuf[8][64][32];   // 64 KB partial-sum exchange
    const int tid  = threadIdx.x;
    const int bid  = blockIdx.x;
    const int wv   = tid >> 6;
    const int l    = tid & 63;
    const int l15  = l & 15;
    const int quad = l >> 4;
    const int ks   = quad * 8;
    const bool isL1 = bid < 128;
    const int colbase = (isL1 ? bid : bid - 128) * 8;
    // B-frag weight rows: nt=0 -> gates {i,f}, nt=1 -> gates {g,o}
    const int row0 = ((l15 >> 3)    ) * H_ + colbase + (l15 & 7);
    const int row1 = ((l15 >> 3) + 2) * H_ + colbase + (l15 & 7);

    auto h1slot = [&](int t) {
        return p.h1seq + (size_t)(RING ? (t & 1) : (t + 1)) * BH_;
    };
    auto h2slot = [&](int t) {
        return p.h2seq + (size_t)(RING ? (t & 3) : (t + 1)) * BH_;
    };

    // Cell duty: threads 0..255, two adjacent cells each (uint h-store).
    const int cm  = tid >> 2;          // batch row
    const int c0  = 2 * (tid & 3);     // first of the col pair
    const int cj0 = colbase + c0;
    const float* bi = isL1 ? p.bih1 : p.bih0;
    const float* bh = isL1 ? p.bhh1 : p.bhh0;
    float bs[8];                       // {i,f,g,o} x {c0, c0+1}
#pragma unroll
    for (int g = 0; g < 4; ++g) {
        bs[2 * g]     = bi[g * H_ + cj0]     + bh[g * H_ + cj0];
        bs[2 * g + 1] = bi[g * H_ + cj0 + 1] + bh[g * H_ + cj0 + 1];
    }
    float creg0 = 0.0f, creg1 = 0.0f;
    const bool outduty = (bid >= 128 && bid < 136);
    const int pbase = (bid - 128) * 16;
    unsigned* const flag = p.cnt + 8 * 64;   // release generation line

    for (int phase = 0; phase < T_ + 2; ++phase) {
        const bool doGemm = isL1 ? (phase >= 1 && phase <= T_) : (phase < T_);
        const int t = isL1 ? phase - 1 : phase;

        if (doGemm) {
            floatx4 acc[8] = {};
            if (isL1) {
                // gates1 = [h1(t) | h2(t-1)] @ [Wih1 | Whh1]^T, K=2048.
                const short* Ab; const short* Wm; int kb;
                if (wv < 4) {
                    Ab = (const short*)h1slot(t);
                    Wm = (const short*)p.Wih1b;  kb = wv * 256;
                } else {
                    Ab = (const short*)h2slot(t - 1);
                    Wm = (const short*)p.Whh1b;  kb = (wv - 4) * 256;
                }
                const short* A  = Ab + kb + ks;
                const short* w0 = Wm + (long)row0 * H_ + kb + ks;
                const short* w1 = Wm + (long)row1 * H_ + kb + ks;
                short8 af[32];
#pragma unroll
                for (int c = 0; c < 8; ++c)
#pragma unroll
                    for (int mt = 0; mt < 4; ++mt)
                        af[c * 4 + mt] = ldA<RING>(A + (long)(mt * 16 + l15) * H_ + c * 32);
#pragma unroll
                for (int c = 0; c < 8; ++c) {
                    short8 b0 = *(const short8*)(w0 + c * 32);
                    short8 b1 = *(const short8*)(w1 + c * 32);
#pragma unroll
                    for (int mt = 0; mt < 4; ++mt) {
                        acc[2 * mt]     = MFMA_(af[c * 4 + mt], b0, acc[2 * mt]);
                        acc[2 * mt + 1] = MFMA_(af[c * 4 + mt], b1, acc[2 * mt + 1]);
                    }
                }
            } else {
                // gates0 = [x_t | h1(t-1)] @ [Wih0 | Whh0]^T, K=128+1024.
                const short* Ah  = (const short*)h1slot(t - 1) + wv * 128 + ks;
                const short* w0h = (const short*)p.Whh0b + (long)row0 * H_ + wv * 128 + ks;
                const short* w1h = (const short*)p.Whh0b + (long)row1 * H_ + wv * 128 + ks;
                const short* Ax; long xstr;
                if (t == 0) { Ax = (const short*)p.stokb; xstr = 0; }
                else { Ax = (const short*)p.tseqb + (long)(t - 1) * P_; xstr = (long)T_ * P_; }
                short8 af[16];
#pragma unroll
                for (int c = 0; c < 4; ++c)
#pragma unroll
                    for (int mt = 0; mt < 4; ++mt)
                        af[c * 4 + mt] = ldA<RING>(Ah + (long)(mt * 16 + l15) * H_ + c * 32);
                short8 xf[4];
                if (wv < 4) {
#pragma unroll
                    for (int mt = 0; mt < 4; ++mt)
                        xf[mt] = *(const short8*)(Ax + (long)(mt * 16 + l15) * xstr + wv * 32 + ks);
                }
#pragma unroll
                for (int c = 0; c < 4; ++c) {
                    short8 b0 = *(const short8*)(w0h + c * 32);
                    short8 b1 = *(const short8*)(w1h + c * 32);
#pragma unroll
                    for (int mt = 0; mt < 4; ++mt) {
                        acc[2 * mt]     = MFMA_(af[c * 4 + mt], b0, acc[2 * mt]);
                        acc[2 * mt + 1] = MFMA_(af[c * 4 + mt], b1, acc[2 * mt + 1]);
                    }
                }
                if (wv < 4) {   // x-part chunk wv
                    short8 b0 = *(const short8*)((const short*)p.Wih0b + (long)row0 * P_ + wv * 32 + ks);
                    short8 b1 = *(const short8*)((const short*)p.Wih0b + (long)row1 * P_ + wv * 32 + ks);
#pragma unroll
                    for (int mt = 0; mt < 4; ++mt) {
                        acc[2 * mt]     = MFMA_(xf[mt], b0, acc[2 * mt]);
                        acc[2 * mt + 1] = MFMA_(xf[mt], b1, acc[2 * mt + 1]);
                    }
                }
            }
            // C/D: col = lane&15, row = quad*4 + reg (+ mt*16)
#pragma unroll
            for (int mt = 0; mt < 4; ++mt)
#pragma unroll
                for (int nt = 0; nt < 2; ++nt)
#pragma unroll
                    for (int r = 0; r < 4; ++r) {
                        int row = mt * 16 + quad * 4 + r;
                        pbuf[wv][row][PBI(nt * 16 + l15, row)] = acc[2 * mt + nt][r];
                    }
        }
        __syncthreads();
        if (doGemm && tid < 256) {
            // gate n-layout: i: [0,8) f: [8,16) g: [16,24) o: [24,32)
            float v[8];
#pragma unroll
            for (int k = 0; k < 8; ++k) v[k] = bs[k];
#pragma unroll
            for (int w2 = 0; w2 < 8; ++w2)
#pragma unroll
                for (int g = 0; g < 4; ++g) {
                    v[2 * g]     += pbuf[w2][cm][PBI(8 * g + c0,     cm)];
                    v[2 * g + 1] += pbuf[w2][cm][PBI(8 * g + c0 + 1, cm)];
                }
            float cn0 = sigmoidf_(v[2]) * creg0 + sigmoidf_(v[0]) * tanh_fast(v[4]);
            float cn1 = sigmoidf_(v[3]) * creg1 + sigmoidf_(v[1]) * tanh_fast(v[5]);
            float hv0 = sigmoidf_(v[6]) * tanh_fast(cn0);
            float hv1 = sigmoidf_(v[7]) * tanh_fast(cn1);
            creg0 = cn0; creg1 = cn1;
            __hip_bfloat16* hdst = isL1 ? h2slot(t) : h1slot(t);
            __hip_bfloat16 hb0 = __float2bfloat16(hv0), hb1 = __float2bfloat16(hv1);
            unsigned pk = ((unsigned)*(unsigned short*)&hb1 << 16) | *(unsigned short*)&hb0;
            // sc1 write-through: LLC is the truth; no dirty line hides in the
            // producer XCD's L2 (required for normal consumer loads, RING=0).
            __hip_atomic_store((unsigned*)(hdst + cm * H_ + cj0), pk,
                               __ATOMIC_RELAXED, __HIP_MEMORY_SCOPE_AGENT);
        }

        if (outduty && phase >= 2) {
            int t2 = phase - 2;
            __syncthreads();   // cell reads of pbuf done; safe to overwrite
            floatx4 oacc[4] = {};
            const short* Ab = (const short*)h2slot(t2) + wv * 128 + ks;
            const short* Wb = (const short*)p.owb + (long)(pbase + l15) * H_ + wv * 128 + ks;
            short8 of[16];
#pragma unroll
            for (int c2 = 0; c2 < 4; ++c2)
#pragma unroll
                for (int mt = 0; mt < 4; ++mt)
                    of[c2 * 4 + mt] = ldA<RING>(Ab + (long)(mt * 16 + l15) * H_ + c2 * 32);
#pragma unroll
            for (int c2 = 0; c2 < 4; ++c2) {
                short8 b0 = *(const short8*)(Wb + c2 * 32);
#pragma unroll
                for (int mt = 0; mt < 4; ++mt)
                    oacc[mt] = MFMA_(of[c2 * 4 + mt], b0, oacc[mt]);
            }
#pragma unroll
            for (int mt = 0; mt < 4; ++mt)
#pragma unroll
                for (int r = 0; r < 4; ++r)
                    pbuf[wv][mt * 16 + quad * 4 + r][l15] = oacc[mt][r];
            __syncthreads();
#pragma unroll
            for (int q2 = 0; q2 < 2; ++q2) {
                int e = tid + q2 * 512, m = e >> 4, pp = e & 15;
                float v = p.ob[pbase + pp];
#pragma unroll
                for (int w2 = 0; w2 < 8; ++w2) v += pbuf[w2][m][pp];
                p.out[(long)m * (T_ * P_) + (long)t2 * P_ + pbase + pp] = sigmoidf_(v);
            }
        }

        // __syncthreads drains each wave's vmcnt(0) (h stores complete at L3)
        __syncthreads();
        if (tid == 0) {
            __hip_atomic_fetch_add(p.cnt + (bid & 7) * 64, 1u,
                                   __ATOMIC_RELAXED, __HIP_MEMORY_SCOPE_AGENT);
            unsigned gen = (unsigned)(phase + 1);
            if (bid == 0) {
                // Leader: aggregate the 8 arrive counters, then publish gen.
                unsigned target = 256u * gen;
                for (;;) {
                    unsigned s = 0;
#pragma unroll
                    for (int i2 = 0; i2 < 8; ++i2)
                        s += __hip_atomic_load(p.cnt + i2 * 64,
                                               __ATOMIC_RELAXED, __HIP_MEMORY_SCOPE_AGENT);
                    if (s >= target) break;
                    __builtin_amdgcn_s_sleep(1);
                }
                asm volatile("" ::: "memory");
                __hip_atomic_store(flag, gen,
                                   __ATOMIC_RELAXED, __HIP_MEMORY_SCOPE_AGENT);
            } else {
                // Everyone else polls ONE line with backoff (no read storm).
                while (__hip_atomic_load(flag, __ATOMIC_RELAXED,
                                         __HIP_MEMORY_SCOPE_AGENT) < gen)
                    __builtin_amdgcn_s_sleep(8);
            }
        }
        asm volatile("" ::: "memory");   // compiler fence: no hoisting past spin
        __syncthreads();
    }
}

// ---------------------------------------------------------------------------
extern "C" void kernel_launch(void* const* d_in, const int* in_sizes, int n_in,
                              void* d_out, int out_size, void* d_ws, size_t ws_size,
                              hipStream_t stream) {
    const float* z    = (const float*)d_in[0];
    const float* tseq = (const float*)d_in[1];
    const float* fw   = (const float*)d_in[2];
    const float* fb   = (const float*)d_in[3];
    const float* stok = (const float*)d_in[4];
    const float* Wih0 = (const float*)d_in[5];
    const float* Whh0 = (const float*)d_in[6];
    const float* bih0 = (const float*)d_in[7];
    const float* bhh0 = (const float*)d_in[8];
    const float* Wih1 = (const float*)d_in[9];
    const float* Whh1 = (const float*)d_in[10];
    const float* bih1 = (const float*)d_in[11];
    const float* bhh1 = (const float*)d_in[12];
    const float* ow   = (const float*)d_in[13];
    const float* ob   = (const float*)d_in[14];
    float* out = (float*)d_out;

    // Static part: weights + tseq + stok (~25.5 MB)
    const size_t SBYTES = (size_t)4 * H_ * P_ * 2 + 3 * ((size_t)4 * H_ * H_ * 2)
                        + (size_t)P_ * H_ * 2 + (size_t)B_ * T_ * P_ * 2 + 256;
    const size_t CNTB = 9 * 256;
    // Preferred mode: write-once h slots, T+1 each (~67.4 MB more).
    const size_t FULLH = (size_t)(T_ + 1) * BH_ * 2;
    bool ring = ws_size < SBYTES + 2 * FULLH + CNTB;
    const size_t H1B = ring ? (size_t)2 * BH_ * 2 : FULLH;
    const size_t H2B = ring ? (size_t)4 * BH_ * 2 : FULLH;

    char* ws = (char*)d_ws;
    size_t off = 0;
    __hip_bfloat16* Wih0b = (__hip_bfloat16*)(ws + off); off += (size_t)4 * H_ * P_ * 2;
    __hip_bfloat16* Whh0b = (__hip_bfloat16*)(ws + off); off += (size_t)4 * H_ * H_ * 2;
    __hip_bfloat16* Wih1b = (__hip_bfloat16*)(ws + off); off += (size_t)4 * H_ * H_ * 2;
    __hip_bfloat16* Whh1b = (__hip_bfloat16*)(ws + off); off += (size_t)4 * H_ * H_ * 2;
    __hip_bfloat16* owb   = (__hip_bfloat16*)(ws + off); off += (size_t)P_ * H_ * 2;
    __hip_bfloat16* tseqb = (__hip_bfloat16*)(ws + off); off += (size_t)B_ * T_ * P_ * 2;
    __hip_bfloat16* stokb = (__hip_bfloat16*)(ws + off); off += 256;
    __hip_bfloat16* h1seq = (__hip_bfloat16*)(ws + off); off += H1B;
    __hip_bfloat16* h2seq = (__hip_bfloat16*)(ws + off); off += H2B;
    unsigned* cnt         = (unsigned*)(ws + off);       off += CNTB;

    auto cvt = [&](const float* s, __hip_bfloat16* d, int n) {
        hipLaunchKernelGGL(cvt_f2b, dim3((n / 4 + 255) / 256), dim3(256), 0, stream, s, d, n);
    };
    cvt(Wih0, Wih0b, 4 * H_ * P_);
    cvt(Whh0, Whh0b, 4 * H_ * H_);
    cvt(Wih1, Wih1b, 4 * H_ * H_);
    cvt(Whh1, Whh1b, 4 * H_ * H_);
    cvt(ow,   owb,   P_ * H_);
    cvt(tseq, tseqb, B_ * T_ * P_);
    cvt(stok, stokb, P_);

    // h0 into the t=-1 slots (full-seq: slot 0; ring: slots 1 / 3).
    __hip_bfloat16* h1m1 = h1seq + (size_t)(ring ? 1 : 0) * BH_;
    __hip_bfloat16* h2m1 = h2seq + (size_t)(ring ? 3 : 0) * BH_;
    hipLaunchKernelGGL(h0_kernel, dim3(256), dim3(256), 0, stream,
                       z, fw, fb, h1m1, h2m1, cnt);

    PParams pp;
    pp.tseqb = tseqb; pp.stokb = stokb;
    pp.Wih0b = Wih0b; pp.Whh0b = Whh0b; pp.Wih1b = Wih1b; pp.Whh1b = Whh1b;
    pp.owb = owb;
    pp.bih0 = bih0; pp.bhh0 = bhh0; pp.bih1 = bih1; pp.bhh1 = bhh1; pp.ob = ob;
    pp.h1seq = h1seq; pp.h2seq = h2seq;
    pp.out = out;
    pp.cnt = cnt;
    void* args[] = { &pp };
    if (ring)
        hipLaunchCooperativeKernel((void*)lstm_persistent<true>, dim3(256), dim3(512),
                                   args, 0, stream);
    else
        hipLaunchCooperativeKernel((void*)lstm_persistent<false>, dim3(256), dim3(512),
                                   args, 0, stream);
}

// Round 9
// 3187.039 us; speedup vs baseline: 1.7845x; 1.1659x over previous
//
#include <hip/hip_runtime.h>
#include <hip/hip_bf16.h>
#include <stdint.h>

typedef __attribute__((ext_vector_type(8))) short short8;
typedef __attribute__((ext_vector_type(4))) float floatx4;

#define B_ 64
#define T_ 256
#define H_ 1024
#define LATENT_ 256
#define P_ 128
#define BH_ (B_ * H_)
#define MFMA_(a, b, c) __builtin_amdgcn_mfma_f32_16x16x32_bf16(a, b, c, 0, 0, 0)
// LDS column swizzle for pbuf: breaks 16-way conflicts on cell-phase reads.
#define PBI(n, row) (((n) + 4 * (row)) & 31)

// Dynamic-LDS partition (bytes): pbuf 64K | Whh slice 64K | Wih0 slice 8K
#define PBUF_OFF 0
#define WHH_OFF  65536
#define WIH0_OFF 131072
#define LDS_TOTAL 139264

__device__ __forceinline__ float sigmoidf_(float x) {
    return 1.0f / (1.0f + __expf(-x));
}
__device__ __forceinline__ float tanh_fast(float x) {
    float e = __expf(2.0f * x);
    return 1.0f - 2.0f / (e + 1.0f);
}

// ---------------------------------------------------------------------------
__global__ __launch_bounds__(256) void cvt_f2b(
    const float* __restrict__ src, __hip_bfloat16* __restrict__ dst, int n)
{
    int i = (blockIdx.x * 256 + threadIdx.x) * 4;
    if (i < n) {
        float4 v = *(const float4*)(src + i);
        dst[i + 0] = __float2bfloat16(v.x);
        dst[i + 1] = __float2bfloat16(v.y);
        dst[i + 2] = __float2bfloat16(v.z);
        dst[i + 3] = __float2bfloat16(v.w);
    }
}

// h0 = z @ fc_init_w^T + fc_init_b -> the two t=-1 slots; zero barrier lines.
__global__ __launch_bounds__(256) void h0_kernel(
    const float* __restrict__ z,
    const float* __restrict__ fw,
    const float* __restrict__ fb,
    __hip_bfloat16* __restrict__ h1dst,
    __hip_bfloat16* __restrict__ h2dst,
    unsigned* __restrict__ cnt)
{
    if (blockIdx.x == 0 && threadIdx.x < 9) cnt[threadIdx.x * 64] = 0;
    int idx = blockIdx.x * 256 + threadIdx.x;   // 0..65535
    int b = idx >> 10, j = idx & 1023;
    const float* zp = z + b * LATENT_;
    const float* wp = fw + j * LATENT_;
    float acc = fb[j];
    for (int k = 0; k < LATENT_; k += 4) {
        float4 zv = *(const float4*)(zp + k);
        float4 wv = *(const float4*)(wp + k);
        acc += zv.x * wv.x + zv.y * wv.y + zv.z * wv.z + zv.w * wv.w;
    }
    __hip_bfloat16 hb = __float2bfloat16(acc);
    h1dst[idx] = hb;
    h2dst[idx] = hb;
}

struct PParams {
    const __hip_bfloat16 *tseqb, *stokb;
    const __hip_bfloat16 *Wih0b, *Whh0b, *Wih1b, *Whh1b, *owb;
    const float *bih0, *bhh0, *bih1, *bhh1, *ob;
    __hip_bfloat16 *h1seq;    // T+1 slots, write-once per t (slot t+1)
    __hip_bfloat16 *h2seq;    // T+1 slots
    float* out;               // (B, T, P)
    unsigned* cnt;            // 8 arrive counters (256B apart) + flag line
};

// ---------------------------------------------------------------------------
// Persistent pipelined LSTM. 256 blocks x 512 threads (8 waves), 1 block/CU.
//   blocks   0..127 : layer-1 step t=phase-1 (8 cols x 4 gates, N=32 rows)
//   blocks 128..255 : layer-0 step t=phase
// R8 post-mortem: per-XCD L2 working set (3.6 MB weights+h) thrashed the
// 4 MB L2 -> 2 MB/phase weight re-fetch inside the MFMA loop + barrier skew.
// Fix: Whh (and Wih0) slices staged in LDS once (XOR-swizzled, conflict-free
// ds_read_b128); Wih1 stays in a now-roomy L2 (1 MB/XCD). Out-projection is
// a post-loop parallel GEMM (1 block per timestep) instead of per-phase
// straggler work on blocks 128-135.
// ---------------------------------------------------------------------------
__global__ __launch_bounds__(512, 2) void lstm_persistent(PParams p)
{
    extern __shared__ char dynlds[];
    float (*pbuf)[64][32] = (float (*)[64][32])(dynlds + PBUF_OFF);
    short8* whh8 = (short8*)(dynlds + WHH_OFF);   // [r*128 + (kc ^ (r&7))]
    short8* wx8  = (short8*)(dynlds + WIH0_OFF);  // [r*16  + (kc ^ (r&7))]

    const int tid  = threadIdx.x;
    const int bid  = blockIdx.x;
    const int wv   = tid >> 6;
    const int l    = tid & 63;
    const int l15  = l & 15;
    const int quad = l >> 4;
    const int ks   = quad * 8;
    const bool isL1 = bid < 128;
    const int colbase = (isL1 ? bid : bid - 128) * 8;
    // B-frag rows: nt=0 -> gates {i,f} (local rows 0..15), nt=1 -> {g,o} (+16)
    const int r0l  = (l15 >> 3) * 8 + (l15 & 7);       // local row, gates 0/1
    const int row0 = ((l15 >> 3)    ) * H_ + colbase + (l15 & 7);  // global
    const int row1 = ((l15 >> 3) + 2) * H_ + colbase + (l15 & 7);

    auto h1slot = [&](int t) { return p.h1seq + (size_t)(t + 1) * BH_; };
    auto h2slot = [&](int t) { return p.h2seq + (size_t)(t + 1) * BH_; };

    // ---- stage recurrent weights into LDS (once) ----
    {
        const short* Wh = (const short*)(isL1 ? p.Whh1b : p.Whh0b);
        for (int i = tid; i < 32 * 128; i += 512) {
            int r = i >> 7, kc = i & 127;
            int grow = (r >> 3) * H_ + colbase + (r & 7);
            whh8[r * 128 + (kc ^ (r & 7))] =
                *(const short8*)(Wh + (size_t)grow * H_ + kc * 8);
        }
        if (!isL1) {
            const short* Wx = (const short*)p.Wih0b;
            for (int i = tid; i < 32 * 16; i += 512) {
                int r = i >> 4, kc = i & 15;
                int grow = (r >> 3) * H_ + colbase + (r & 7);
                wx8[r * 16 + (kc ^ (r & 7))] =
                    *(const short8*)(Wx + (size_t)grow * P_ + kc * 8);
            }
        }
    }
    __syncthreads();

    // Cell duty: threads 0..255, two adjacent cells each (uint h-store).
    const int cm  = tid >> 2;          // batch row
    const int c0  = 2 * (tid & 3);     // first of the col pair
    const int cj0 = colbase + c0;
    const float* bi = isL1 ? p.bih1 : p.bih0;
    const float* bh = isL1 ? p.bhh1 : p.bhh0;
    float bs[8];                       // {i,f,g,o} x {c0, c0+1}
#pragma unroll
    for (int g = 0; g < 4; ++g) {
        bs[2 * g]     = bi[g * H_ + cj0]     + bh[g * H_ + cj0];
        bs[2 * g + 1] = bi[g * H_ + cj0 + 1] + bh[g * H_ + cj0 + 1];
    }
    float creg0 = 0.0f, creg1 = 0.0f;
    unsigned* const flag = p.cnt + 8 * 64;   // release generation line

    for (int phase = 0; phase <= T_; ++phase) {
        const bool doGemm = isL1 ? (phase >= 1) : (phase < T_);
        const int t = isL1 ? phase - 1 : phase;

        if (doGemm) {
            floatx4 acc[8] = {};
            if (isL1) {
                // gates1 = [h1(t) | h2(t-1)] @ [Wih1 | Whh1]^T, K=2048.
                if (wv < 4) {
                    // Wih1 half from L2 (now resident: 1 MB/XCD footprint)
                    const short* A  = (const short*)h1slot(t) + wv * 256 + ks;
                    const short* w0 = (const short*)p.Wih1b + (long)row0 * H_ + wv * 256 + ks;
                    const short* w1 = (const short*)p.Wih1b + (long)row1 * H_ + wv * 256 + ks;
                    short8 af[32];
#pragma unroll
                    for (int c = 0; c < 8; ++c)
#pragma unroll
                        for (int mt = 0; mt < 4; ++mt)
                            af[c * 4 + mt] = *(const short8*)(A + (long)(mt * 16 + l15) * H_ + c * 32);
#pragma unroll
                    for (int c = 0; c < 8; ++c) {
                        short8 b0 = *(const short8*)(w0 + c * 32);
                        short8 b1 = *(const short8*)(w1 + c * 32);
#pragma unroll
                        for (int mt = 0; mt < 4; ++mt) {
                            acc[2 * mt]     = MFMA_(af[c * 4 + mt], b0, acc[2 * mt]);
                            acc[2 * mt + 1] = MFMA_(af[c * 4 + mt], b1, acc[2 * mt + 1]);
                        }
                    }
                } else {
                    // Whh1 half from LDS
                    const short* A = (const short*)h2slot(t - 1) + (wv - 4) * 256 + ks;
                    short8 af[32];
#pragma unroll
                    for (int c = 0; c < 8; ++c)
#pragma unroll
                        for (int mt = 0; mt < 4; ++mt)
                            af[c * 4 + mt] = *(const short8*)(A + (long)(mt * 16 + l15) * H_ + c * 32);
#pragma unroll
                    for (int c = 0; c < 8; ++c) {
                        int kcq = (wv - 4) * 32 + quad + c * 4;
                        short8 b0 = whh8[r0l * 128 + (kcq ^ (r0l & 7))];
                        short8 b1 = whh8[(r0l + 16) * 128 + (kcq ^ (r0l & 7))];
#pragma unroll
                        for (int mt = 0; mt < 4; ++mt) {
                            acc[2 * mt]     = MFMA_(af[c * 4 + mt], b0, acc[2 * mt]);
                            acc[2 * mt + 1] = MFMA_(af[c * 4 + mt], b1, acc[2 * mt + 1]);
                        }
                    }
                }
            } else {
                // gates0 = [x_t | h1(t-1)] @ [Wih0 | Whh0]^T, K=128+1024.
                const short* Ah = (const short*)h1slot(t - 1) + wv * 128 + ks;
                const short* Ax; long xstr;
                if (t == 0) { Ax = (const short*)p.stokb; xstr = 0; }
                else { Ax = (const short*)p.tseqb + (long)(t - 1) * P_; xstr = (long)T_ * P_; }
                short8 af[16];
#pragma unroll
                for (int c = 0; c < 4; ++c)
#pragma unroll
                    for (int mt = 0; mt < 4; ++mt)
                        af[c * 4 + mt] = *(const short8*)(Ah + (long)(mt * 16 + l15) * H_ + c * 32);
                short8 xf[4];
                if (wv < 4) {
#pragma unroll
                    for (int mt = 0; mt < 4; ++mt)
                        xf[mt] = *(const short8*)(Ax + (long)(mt * 16 + l15) * xstr + wv * 32 + ks);
                }
#pragma unroll
                for (int c = 0; c < 4; ++c) {
                    int kcq = wv * 16 + quad + c * 4;
                    short8 b0 = whh8[r0l * 128 + (kcq ^ (r0l & 7))];
                    short8 b1 = whh8[(r0l + 16) * 128 + (kcq ^ (r0l & 7))];
#pragma unroll
                    for (int mt = 0; mt < 4; ++mt) {
                        acc[2 * mt]     = MFMA_(af[c * 4 + mt], b0, acc[2 * mt]);
                        acc[2 * mt + 1] = MFMA_(af[c * 4 + mt], b1, acc[2 * mt + 1]);
                    }
                }
                if (wv < 4) {   // x-part chunk wv (Wih0 from LDS)
                    int kcx = wv * 4 + quad;
                    short8 b0 = wx8[r0l * 16 + (kcx ^ (r0l & 7))];
                    short8 b1 = wx8[(r0l + 16) * 16 + (kcx ^ (r0l & 7))];
#pragma unroll
                    for (int mt = 0; mt < 4; ++mt) {
                        acc[2 * mt]     = MFMA_(xf[mt], b0, acc[2 * mt]);
                        acc[2 * mt + 1] = MFMA_(xf[mt], b1, acc[2 * mt + 1]);
                    }
                }
            }
            // C/D: col = lane&15, row = quad*4 + reg (+ mt*16)
#pragma unroll
            for (int mt = 0; mt < 4; ++mt)
#pragma unroll
                for (int nt = 0; nt < 2; ++nt)
#pragma unroll
                    for (int r = 0; r < 4; ++r) {
                        int row = mt * 16 + quad * 4 + r;
                        pbuf[wv][row][PBI(nt * 16 + l15, row)] = acc[2 * mt + nt][r];
                    }
        }
        __syncthreads();
        if (doGemm && tid < 256) {
            // gate n-layout: i: [0,8) f: [8,16) g: [16,24) o: [24,32)
            float v[8];
#pragma unroll
            for (int k = 0; k < 8; ++k) v[k] = bs[k];
#pragma unroll
            for (int w2 = 0; w2 < 8; ++w2)
#pragma unroll
                for (int g = 0; g < 4; ++g) {
                    v[2 * g]     += pbuf[w2][cm][PBI(8 * g + c0,     cm)];
                    v[2 * g + 1] += pbuf[w2][cm][PBI(8 * g + c0 + 1, cm)];
                }
            float cn0 = sigmoidf_(v[2]) * creg0 + sigmoidf_(v[0]) * tanh_fast(v[4]);
            float cn1 = sigmoidf_(v[3]) * creg1 + sigmoidf_(v[1]) * tanh_fast(v[5]);
            float hv0 = sigmoidf_(v[6]) * tanh_fast(cn0);
            float hv1 = sigmoidf_(v[7]) * tanh_fast(cn1);
            creg0 = cn0; creg1 = cn1;
            __hip_bfloat16* hdst = isL1 ? h2slot(t) : h1slot(t);
            __hip_bfloat16 hb0 = __float2bfloat16(hv0), hb1 = __float2bfloat16(hv1);
            unsigned pk = ((unsigned)*(unsigned short*)&hb1 << 16) | *(unsigned short*)&hb0;
            // sc1 write-through: LLC holds the truth; no dirty line hides in
            // the producer XCD's L2 (required for normal consumer loads).
            __hip_atomic_store((unsigned*)(hdst + cm * H_ + cj0), pk,
                               __ATOMIC_RELAXED, __HIP_MEMORY_SCOPE_AGENT);
        }

        // __syncthreads drains each wave's vmcnt(0) (h stores complete at L3)
        __syncthreads();
        if (tid == 0) {
            __hip_atomic_fetch_add(p.cnt + (bid & 7) * 64, 1u,
                                   __ATOMIC_RELAXED, __HIP_MEMORY_SCOPE_AGENT);
            unsigned gen = (unsigned)(phase + 1);
            if (bid == 255) {
                // Leader is an L0 block (finishes early): aggregate + publish.
                unsigned target = 256u * gen;
                for (;;) {
                    unsigned s = 0;
#pragma unroll
                    for (int i2 = 0; i2 < 8; ++i2)
                        s += __hip_atomic_load(p.cnt + i2 * 64,
                                               __ATOMIC_RELAXED, __HIP_MEMORY_SCOPE_AGENT);
                    if (s >= target) break;
                    __builtin_amdgcn_s_sleep(1);
                }
                asm volatile("" ::: "memory");
                __hip_atomic_store(flag, gen,
                                   __ATOMIC_RELAXED, __HIP_MEMORY_SCOPE_AGENT);
            } else {
                while (__hip_atomic_load(flag, __ATOMIC_RELAXED,
                                         __HIP_MEMORY_SCOPE_AGENT) < gen)
                    __builtin_amdgcn_s_sleep(8);
            }
        }
        asm volatile("" ::: "memory");   // compiler fence: no hoisting past spin
        __syncthreads();
    }

    // ---- Post-loop output projection: one block per timestep t = bid ----
    // out[:, t, :] = sigmoid(h2(t) @ ow^T + ob); M=64, N=128, K=1024.
    // Wave (nh = wv>>1, kh = wv&1): N=32 (2 B-frags), K=512.
    {
        const int t = bid;
        const int nh = wv >> 1, kh = wv & 1;
        const short* A  = (const short*)h2slot(t);
        const short* Wb = (const short*)p.owb;
        floatx4 oacc[8] = {};
        for (int c = 0; c < 16; ++c) {
            int kk = kh * 512 + c * 32 + ks;
            short8 b0 = *(const short8*)(Wb + (long)(nh * 32 + l15) * H_ + kk);
            short8 b1 = *(const short8*)(Wb + (long)(nh * 32 + 16 + l15) * H_ + kk);
#pragma unroll
            for (int mt = 0; mt < 4; ++mt) {
                short8 a = *(const short8*)(A + (long)(mt * 16 + l15) * H_ + kk);
                oacc[2 * mt]     = MFMA_(a, b0, oacc[2 * mt]);
                oacc[2 * mt + 1] = MFMA_(a, b1, oacc[2 * mt + 1]);
            }
        }
#pragma unroll
        for (int mt = 0; mt < 4; ++mt)
#pragma unroll
            for (int nt = 0; nt < 2; ++nt)
#pragma unroll
                for (int r = 0; r < 4; ++r) {
                    int row = mt * 16 + quad * 4 + r;
                    pbuf[wv][row][PBI(nt * 16 + l15, row)] = oacc[2 * mt + nt][r];
                }
        __syncthreads();
        for (int i = tid; i < 64 * 128; i += 512) {
            int m = i >> 7, pp2 = i & 127;
            int nh2 = pp2 >> 5, pc = pp2 & 31;
            float v = pbuf[2 * nh2][m][PBI(pc, m)] + pbuf[2 * nh2 + 1][m][PBI(pc, m)]
                    + p.ob[pp2];
            p.out[(long)m * (T_ * P_) + (long)t * P_ + pp2] = sigmoidf_(v);
        }
    }
}

// ---------------------------------------------------------------------------
extern "C" void kernel_launch(void* const* d_in, const int* in_sizes, int n_in,
                              void* d_out, int out_size, void* d_ws, size_t ws_size,
                              hipStream_t stream) {
    const float* z    = (const float*)d_in[0];
    const float* tseq = (const float*)d_in[1];
    const float* fw   = (const float*)d_in[2];
    const float* fb   = (const float*)d_in[3];
    const float* stok = (const float*)d_in[4];
    const float* Wih0 = (const float*)d_in[5];
    const float* Whh0 = (const float*)d_in[6];
    const float* bih0 = (const float*)d_in[7];
    const float* bhh0 = (const float*)d_in[8];
    const float* Wih1 = (const float*)d_in[9];
    const float* Whh1 = (const float*)d_in[10];
    const float* bih1 = (const float*)d_in[11];
    const float* bhh1 = (const float*)d_in[12];
    const float* ow   = (const float*)d_in[13];
    const float* ob   = (const float*)d_in[14];
    float* out = (float*)d_out;

    // Workspace (~93.2 MB; confirmed available in R8 — MODE0 ran).
    const size_t FULLH = (size_t)(T_ + 1) * BH_ * 2;
    char* ws = (char*)d_ws;
    size_t off = 0;
    __hip_bfloat16* Wih0b = (__hip_bfloat16*)(ws + off); off += (size_t)4 * H_ * P_ * 2;
    __hip_bfloat16* Whh0b = (__hip_bfloat16*)(ws + off); off += (size_t)4 * H_ * H_ * 2;
    __hip_bfloat16* Wih1b = (__hip_bfloat16*)(ws + off); off += (size_t)4 * H_ * H_ * 2;
    __hip_bfloat16* Whh1b = (__hip_bfloat16*)(ws + off); off += (size_t)4 * H_ * H_ * 2;
    __hip_bfloat16* owb   = (__hip_bfloat16*)(ws + off); off += (size_t)P_ * H_ * 2;
    __hip_bfloat16* tseqb = (__hip_bfloat16*)(ws + off); off += (size_t)B_ * T_ * P_ * 2;
    __hip_bfloat16* stokb = (__hip_bfloat16*)(ws + off); off += 256;
    __hip_bfloat16* h1seq = (__hip_bfloat16*)(ws + off); off += FULLH;
    __hip_bfloat16* h2seq = (__hip_bfloat16*)(ws + off); off += FULLH;
    unsigned* cnt         = (unsigned*)(ws + off);       off += 9 * 256;

    auto cvt = [&](const float* s, __hip_bfloat16* d, int n) {
        hipLaunchKernelGGL(cvt_f2b, dim3((n / 4 + 255) / 256), dim3(256), 0, stream, s, d, n);
    };
    cvt(Wih0, Wih0b, 4 * H_ * P_);
    cvt(Whh0, Whh0b, 4 * H_ * H_);
    cvt(Wih1, Wih1b, 4 * H_ * H_);
    cvt(Whh1, Whh1b, 4 * H_ * H_);
    cvt(ow,   owb,   P_ * H_);
    cvt(tseq, tseqb, B_ * T_ * P_);
    cvt(stok, stokb, P_);

    // h0 into the t=-1 slots (slot 0 of each sequence).
    hipLaunchKernelGGL(h0_kernel, dim3(256), dim3(256), 0, stream,
                       z, fw, fb, h1seq, h2seq, cnt);

    PParams pp;
    pp.tseqb = tseqb; pp.stokb = stokb;
    pp.Wih0b = Wih0b; pp.Whh0b = Whh0b; pp.Wih1b = Wih1b; pp.Whh1b = Whh1b;
    pp.owb = owb;
    pp.bih0 = bih0; pp.bhh0 = bhh0; pp.bih1 = bih1; pp.bhh1 = bhh1; pp.ob = ob;
    pp.h1seq = h1seq; pp.h2seq = h2seq;
    pp.out = out;
    pp.cnt = cnt;

    // 136 KB dynamic LDS (<= 160 KiB/CU on gfx950); must raise the cap first.
    hipFuncSetAttribute((const void*)lstm_persistent,
                        hipFuncAttributeMaxDynamicSharedMemorySize, LDS_TOTAL);
    void* args[] = { &pp };
    hipLaunchCooperativeKernel((void*)lstm_persistent, dim3(256), dim3(512),
                               args, LDS_TOTAL, stream);
}